// Round 1
// 338.195 us; speedup vs baseline: 1.5742x; 1.5742x over previous
//
#include <hip/hip_runtime.h>

typedef unsigned short u16;
typedef __bf16 bf16x8 __attribute__((ext_vector_type(8)));
typedef float f32x4 __attribute__((ext_vector_type(4)));

static constexpr int BB = 16;    // batch
static constexpr int CC = 512;   // channels
static constexpr int SS = 1024;  // seq
static constexpr int R  = 256;   // q-chunk rows (small-ws fallback path)

__device__ __forceinline__ u16 f2bf(float f) {
  __bf16 h = (__bf16)f; return __builtin_bit_cast(unsigned short, h);
}
__device__ __forceinline__ float bf2f(u16 u) {
  union { unsigned int i; float f; } v; v.i = ((unsigned int)u) << 16; return v.f;
}
__device__ __forceinline__ void split2(float v, u16& hi, u16& lo) {
  __bf16 h = (__bf16)v;
  float hf = (float)h;
  __bf16 l = (__bf16)(v - hf);
  hi = __builtin_bit_cast(unsigned short, h);
  lo = __builtin_bit_cast(unsigned short, l);
}

// async global->LDS, 16B per lane; LDS dest = wave-uniform base + lane*16
__device__ __forceinline__ void gld16(const u16* g, u16* l) {
  __builtin_amdgcn_global_load_lds(
      (const __attribute__((address_space(1))) void*)g,
      (__attribute__((address_space(3))) void*)l, 16, 0, 0);
}

// ---------------- BatchNorm stats per channel over (B,S), fp64 ----------------
__global__ __launch_bounds__(256) void bn_stats_f64(const float* __restrict__ x, double* __restrict__ stats) {
  const int c = blockIdx.x;
  double s = 0.0, s2 = 0.0;
  for (int n = threadIdx.x; n < BB * SS; n += 256) {
    int b = n >> 10, sp = n & (SS - 1);
    double v = (double)x[((long long)(b * CC + c)) * SS + sp];
    s += v; s2 += v * v;
  }
  __shared__ double sh[256], sh2[256];
  sh[threadIdx.x] = s; sh2[threadIdx.x] = s2;
  __syncthreads();
  for (int off = 128; off > 0; off >>= 1) {
    if (threadIdx.x < off) { sh[threadIdx.x] += sh[threadIdx.x + off]; sh2[threadIdx.x] += sh2[threadIdx.x + off]; }
    __syncthreads();
  }
  if (threadIdx.x == 0) {
    double mean = sh[0] / 16384.0;
    double var = sh2[0] / 16384.0 - mean * mean;   // biased (torch BN)
    stats[c] = mean;
    stats[CC + c] = 1.0 / sqrt(var + 1e-5);
  }
}

// ---------------- normalize + transpose + split: x [b,c,s] -> xnh/xnl bf16 [b*S + s][c] ----------------
__global__ __launch_bounds__(256) void bn_apply_split(const float* __restrict__ x,
                                                      const double* __restrict__ stats,
                                                      u16* __restrict__ xnh, u16* __restrict__ xnl) {
  __shared__ float tile[64][65];
  const int b = blockIdx.z;
  const int s0 = blockIdx.x * 64, c0 = blockIdx.y * 64;
  const int t = threadIdx.x & 63, rb = threadIdx.x >> 6;
#pragma unroll
  for (int r0 = 0; r0 < 64; r0 += 4) {
    int r = r0 + rb;
    int c = c0 + r;
    double v = (double)x[((long long)(b * CC + c)) * SS + s0 + t];
    tile[r][t] = (float)((v - stats[c]) * stats[CC + c]);
  }
  __syncthreads();
#pragma unroll
  for (int r0 = 0; r0 < 64; r0 += 4) {
    int r = r0 + rb;
    long long idx = ((long long)(b * SS + s0 + r)) * CC + c0 + t;
    u16 h, l; split2(tile[t][r], h, l);
    xnh[idx] = h; xnl[idx] = l;
  }
}

// ---------------- fp32 [n] -> bf16 hi/lo planes ----------------
__global__ __launch_bounds__(256) void conv_split(const float* __restrict__ src,
                                                  u16* __restrict__ h, u16* __restrict__ l) {
  int i = (blockIdx.x * 256 + threadIdx.x) * 4;
  float4 f = *reinterpret_cast<const float4*>(src + i);
  ushort4 H, L;
  split2(f.x, H.x, L.x); split2(f.y, H.y, L.y); split2(f.z, H.z, L.z); split2(f.w, H.w, L.w);
  *reinterpret_cast<ushort4*>(h + i) = H;
  *reinterpret_cast<ushort4*>(l + i) = L;
}

// ---------------- V fp32 [c][d] -> Vt bf16 [d][c] ----------------
__global__ __launch_bounds__(256) void trans_conv_v(const float* __restrict__ V, u16* __restrict__ Vt) {
  __shared__ float tile[64][65];
  const int c0 = blockIdx.x * 64, d0 = blockIdx.y * 64;
  const int t = threadIdx.x & 63, rb = threadIdx.x >> 6;
#pragma unroll
  for (int r0 = 0; r0 < 64; r0 += 4) {
    int r = r0 + rb;
    tile[r][t] = V[(long long)(c0 + r) * 512 + d0 + t];
  }
  __syncthreads();
#pragma unroll
  for (int r0 = 0; r0 < 64; r0 += 4) {
    int r = r0 + rb;
    Vt[(long long)(d0 + r) * 512 + c0 + t] = f2bf(tile[t][r]);
  }
}

// ---------------- MFMA NT GEMM, 128x128 tile, BK=32, global_load_lds staging ----------------
// C[z][m][n] = sum_k A[z][m][k] * Bt[z][n][k]  (split planes approximate fp32 inputs; lo*lo dropped)
// OUTMODE 0: fp32 = acc*scale. 1: bf16. 2: split hi/lo to C,C2. 3: fp32 = acc + (Rh+Rl) residual.
template <bool ASPLIT, bool BSPLIT, int OUTMODE>
__global__ __launch_bounds__(256) void mfma_nt(
    const u16* __restrict__ Ah, const u16* __restrict__ Al, long long sA,
    const u16* __restrict__ Bh, const u16* __restrict__ Bl, long long sB,
    void* __restrict__ C, void* __restrict__ C2, long long sC,
    int N, int K, float scale, const u16* __restrict__ Rh, const u16* __restrict__ Rl) {
  __shared__ __attribute__((aligned(16))) u16 lah[128 * 32];
  __shared__ __attribute__((aligned(16))) u16 lal[ASPLIT ? 128 * 32 : 8];
  __shared__ __attribute__((aligned(16))) u16 lbh[128 * 32];
  __shared__ __attribute__((aligned(16))) u16 lbl[BSPLIT ? 128 * 32 : 8];

  const int tid = threadIdx.x;
  const int z = blockIdx.z;
  const int m0 = blockIdx.y * 128, n0 = blockIdx.x * 128;
  const int wave = tid >> 6, lane = tid & 63;
  const int wr = (wave >> 1) * 64, wc = (wave & 1) * 64;
  const int lrow = lane & 15, lquad = lane >> 4;
  const long long aB = (long long)z * sA, bB = (long long)z * sB;
  const int srow = tid >> 2, scg = (tid & 3) * 8;
  const int wofs = wave * 512;  // u16 units: wave-uniform LDS base (lane i lands at wofs*2 + i*16 bytes)

  f32x4 acc[4][4];
#pragma unroll
  for (int i = 0; i < 4; i++)
#pragma unroll
    for (int j = 0; j < 4; j++) acc[i][j] = (f32x4){0.f, 0.f, 0.f, 0.f};

  for (int k0 = 0; k0 < K; k0 += 32) {
    const long long ar1 = aB + (long long)(m0 + srow) * K + k0 + scg;
    const long long ar2 = aB + (long long)(m0 + srow + 64) * K + k0 + scg;
    gld16(Ah + ar1, &lah[wofs]);
    gld16(Ah + ar2, &lah[wofs + 2048]);
    if constexpr (ASPLIT) {
      gld16(Al + ar1, &lal[wofs]);
      gld16(Al + ar2, &lal[wofs + 2048]);
    }
    const long long br1 = bB + (long long)(n0 + srow) * K + k0 + scg;
    const long long br2 = bB + (long long)(n0 + srow + 64) * K + k0 + scg;
    gld16(Bh + br1, &lbh[wofs]);
    gld16(Bh + br2, &lbh[wofs + 2048]);
    if constexpr (BSPLIT) {
      gld16(Bl + br1, &lbl[wofs]);
      gld16(Bl + br2, &lbl[wofs + 2048]);
    }
    __syncthreads();

    bf16x8 ah[4], al[ASPLIT ? 4 : 1], bh[4], bl[BSPLIT ? 4 : 1];
#pragma unroll
    for (int i = 0; i < 4; i++) {
      ah[i] = *reinterpret_cast<const bf16x8*>(&lah[(wr + i * 16 + lrow) * 32 + lquad * 8]);
      if constexpr (ASPLIT)
        al[i] = *reinterpret_cast<const bf16x8*>(&lal[(wr + i * 16 + lrow) * 32 + lquad * 8]);
      bh[i] = *reinterpret_cast<const bf16x8*>(&lbh[(wc + i * 16 + lrow) * 32 + lquad * 8]);
      if constexpr (BSPLIT)
        bl[i] = *reinterpret_cast<const bf16x8*>(&lbl[(wc + i * 16 + lrow) * 32 + lquad * 8]);
    }
#pragma unroll
    for (int i = 0; i < 4; i++)
#pragma unroll
      for (int j = 0; j < 4; j++) {
        f32x4 t = acc[i][j];
        if constexpr (ASPLIT) t = __builtin_amdgcn_mfma_f32_16x16x32_bf16(al[i], bh[j], t, 0, 0, 0);
        if constexpr (BSPLIT) t = __builtin_amdgcn_mfma_f32_16x16x32_bf16(ah[i], bl[j], t, 0, 0, 0);
        t = __builtin_amdgcn_mfma_f32_16x16x32_bf16(ah[i], bh[j], t, 0, 0, 0);
        acc[i][j] = t;
      }
    __syncthreads();
  }

  const long long zC = (long long)z * sC;
#pragma unroll
  for (int i = 0; i < 4; i++) {
    int rl_ = wr + i * 16 + lquad * 4;
#pragma unroll
    for (int j = 0; j < 4; j++) {
      int col = n0 + wc + j * 16 + lrow;
#pragma unroll
      for (int r = 0; r < 4; r++) {
        long long idx = zC + (long long)(m0 + rl_ + r) * N + col;
        float val = acc[i][j][r];
        if constexpr (OUTMODE == 0) {
          reinterpret_cast<float*>(C)[idx] = val * scale;
        } else if constexpr (OUTMODE == 1) {
          reinterpret_cast<u16*>(C)[idx] = f2bf(val);
        } else if constexpr (OUTMODE == 2) {
          u16 h, l; split2(val, h, l);
          reinterpret_cast<u16*>(C)[idx] = h;
          reinterpret_cast<u16*>(C2)[idx] = l;
        } else {
          reinterpret_cast<float*>(C)[idx] = val + bf2f(Rh[idx]) + bf2f(Rl[idx]);
        }
      }
    }
  }
}

// ---------------- softmax over batch axis: scomp fp32 -> attw bf16 ----------------
__global__ __launch_bounds__(256) void softmax_chunk(const float* __restrict__ sc,
                                                     u16* __restrict__ w, long long plane) {
  long long idx = (long long)blockIdx.x * 256 + threadIdx.x;
  float v[16];
  float m = -3.4e38f;
#pragma unroll
  for (int b = 0; b < 16; b++) { v[b] = sc[(long long)b * plane + idx]; m = fmaxf(m, v[b]); }
  float s = 0.f;
#pragma unroll
  for (int b = 0; b < 16; b++) { v[b] = expf(v[b] - m); s += v[b]; }
  float inv = 1.f / s;
#pragma unroll
  for (int b = 0; b < 16; b++) w[(long long)b * plane + idx] = f2bf(v[b] * inv);
}

extern "C" void kernel_launch(void* const* d_in, const int* in_sizes, int n_in,
                              void* d_out, int out_size, void* d_ws, size_t ws_size,
                              hipStream_t stream) {
  (void)in_sizes; (void)n_in; (void)out_size;
  const float* x  = (const float*)d_in[0];
  const float* Qw = (const float*)d_in[1];
  const float* Kw = (const float*)d_in[2];
  const float* Vw = (const float*)d_in[3];
  float* out = (float*)d_out;
  char* ws = (char*)d_ws;

  const float scale = 0.04419417382415922f;  // 1/sqrt(512)

  // ---- big layout (unchunked): needs 188,235,776 B; ws poison fill suggests 256 MiB ----
  if (ws_size >= 188235776ULL) {
    double* stats = (double*)(ws + 256);
    u16* xnh  = (u16*)(ws + 16384);
    u16* xnl  = (u16*)(ws + 16793600);
    u16* Vt   = (u16*)(ws + 33570816);
    u16* W2th = (u16*)(ws + 34095104);
    u16* W2tl = (u16*)(ws + 34619392);
    u16* Qh   = (u16*)(ws + 35143680);
    u16* Ql   = (u16*)(ws + 35667968);
    u16* Kh   = (u16*)(ws + 36192256);
    u16* Kl   = (u16*)(ws + 36716544);
    u16* vt   = (u16*)(ws + 37240832);   // [16,512,1024] bf16  16 MB
    u16* th   = (u16*)(ws + 54018048);   // [16,1024,512] hi    16 MB
    u16* tl   = (u16*)(ws + 70795264);   // lo                  16 MB
    float* scomp = (float*)(ws + 87572480);   // [16,1024,1024] fp32  64 MB
    u16* attw = (u16*)(ws + 154681344);  // [16,1024,1024] bf16  32 MB

    bn_stats_f64<<<CC, 256, 0, stream>>>(x, stats);
    bn_apply_split<<<dim3(16, 8, 16), 256, 0, stream>>>(x, stats, xnh, xnl);
    conv_split<<<256, 256, 0, stream>>>(Qw, Qh, Ql);
    conv_split<<<256, 256, 0, stream>>>(Kw, Kh, Kl);
    trans_conv_v<<<dim3(8, 8), 256, 0, stream>>>(Vw, Vt);

    // W2t[c'][c] = sum_d K[c',d] Q[c,d]
    mfma_nt<true, true, 2><<<dim3(4, 4, 1), 256, 0, stream>>>(
        Kh, Kl, 0, Qh, Ql, 0, W2th, W2tl, 0, 512, 512, 1.0f, nullptr, nullptr);

    // vt[b][d][token] = sum_c Vt[d,c] * xn[b,token,c]
    mfma_nt<false, true, 1><<<dim3(8, 4, 16), 256, 0, stream>>>(
        Vt, nullptr, 0, xnh, xnl, 524288, vt, nullptr, 524288, 1024, 512, 1.0f, nullptr, nullptr);

    // t[b,s,c'] = sum_c xn[b,s,c] * W2t[c'][c]   full S, 512 blocks
    mfma_nt<true, true, 2><<<dim3(4, 8, 16), 256, 0, stream>>>(
        xnh, xnl, 524288, W2th, W2tl, 0, th, tl, 524288, 512, 512, 1.0f, nullptr, nullptr);

    // scores[b,s,j] = scale * sum_c' t[b,s,c'] * xn[b,j,c']   full S, 1024 blocks
    mfma_nt<true, true, 0><<<dim3(8, 8, 16), 256, 0, stream>>>(
        th, tl, 524288, xnh, xnl, 524288, scomp, nullptr, 1048576,
        1024, 512, scale, nullptr, nullptr);

    softmax_chunk<<<4096, 256, 0, stream>>>(scomp, attw, 1048576LL);

    // out[b,s,d] = sum_k attw[b,s,k] * vt[b,d,k] + xn residual   512 blocks
    mfma_nt<false, false, 3><<<dim3(4, 8, 16), 256, 0, stream>>>(
        attw, nullptr, 1048576, vt, nullptr, 524288,
        out, nullptr, 524288, 512, 1024, 1.0f, xnh, xnl);
    return;
  }

  // ---- fallback: proven chunked layout (85,475,328 B) ----
  double* stats = (double*)(ws + 256);
  u16* xnh  = (u16*)(ws + 16384);
  u16* xnl  = (u16*)(ws + 16793600);
  u16* Vt   = (u16*)(ws + 33570816);
  u16* W2th = (u16*)(ws + 34095104);
  u16* W2tl = (u16*)(ws + 34619392);
  u16* vt   = (u16*)(ws + 35143680);
  u16* th   = (u16*)(ws + 51920896);
  u16* tl   = (u16*)(ws + 56115200);
  float* scomp = (float*)(ws + 60309504);
  u16* attw = (u16*)(ws + 77086720);
  u16* Qh = (u16*)(ws + 51920896);
  u16* Ql = (u16*)(ws + 52445184);
  u16* Kh = (u16*)(ws + 52969472);
  u16* Kl = (u16*)(ws + 53493760);

  bn_stats_f64<<<CC, 256, 0, stream>>>(x, stats);
  bn_apply_split<<<dim3(16, 8, 16), 256, 0, stream>>>(x, stats, xnh, xnl);
  conv_split<<<256, 256, 0, stream>>>(Qw, Qh, Ql);
  conv_split<<<256, 256, 0, stream>>>(Kw, Kh, Kl);
  trans_conv_v<<<dim3(8, 8), 256, 0, stream>>>(Vw, Vt);

  mfma_nt<true, true, 2><<<dim3(4, 4, 1), 256, 0, stream>>>(
      Kh, Kl, 0, Qh, Ql, 0, W2th, W2tl, 0, 512, 512, 1.0f, nullptr, nullptr);

  mfma_nt<false, true, 1><<<dim3(8, 4, 16), 256, 0, stream>>>(
      Vt, nullptr, 0, xnh, xnl, 524288, vt, nullptr, 524288, 1024, 512, 1.0f, nullptr, nullptr);

  for (int ci = 0; ci < 4; ci++) {
    int s0c = ci * R;
    mfma_nt<true, true, 2><<<dim3(4, 2, 16), 256, 0, stream>>>(
        xnh + (long long)s0c * 512, xnl + (long long)s0c * 512, 524288,
        W2th, W2tl, 0, th, tl, 131072, 512, 512, 1.0f, nullptr, nullptr);
    mfma_nt<true, true, 0><<<dim3(8, 2, 16), 256, 0, stream>>>(
        th, tl, 131072, xnh, xnl, 524288, scomp, nullptr, 262144,
        1024, 512, scale, nullptr, nullptr);
    softmax_chunk<<<1024, 256, 0, stream>>>(scomp, attw, 262144LL);
    mfma_nt<false, false, 3><<<dim3(4, 2, 16), 256, 0, stream>>>(
        attw, nullptr, 262144, vt, nullptr, 524288,
        out + (long long)s0c * 512, nullptr, 524288, 512, 1024, 1.0f,
        xnh + (long long)s0c * 512, xnl + (long long)s0c * 512);
  }
}

// Round 2
// 316.181 us; speedup vs baseline: 1.6838x; 1.0696x over previous
//
#include <hip/hip_runtime.h>

typedef unsigned short u16;
typedef __bf16 bf16x8 __attribute__((ext_vector_type(8)));
typedef float f32x4 __attribute__((ext_vector_type(4)));

static constexpr int BB = 16;    // batch
static constexpr int CC = 512;   // channels
static constexpr int SS = 1024;  // seq
static constexpr int R  = 256;   // q-chunk rows (small-ws fallback path)

__device__ __forceinline__ u16 f2bf(float f) {
  __bf16 h = (__bf16)f; return __builtin_bit_cast(unsigned short, h);
}
__device__ __forceinline__ float bf2f(u16 u) {
  union { unsigned int i; float f; } v; v.i = ((unsigned int)u) << 16; return v.f;
}
__device__ __forceinline__ void split2(float v, u16& hi, u16& lo) {
  __bf16 h = (__bf16)v;
  float hf = (float)h;
  __bf16 l = (__bf16)(v - hf);
  hi = __builtin_bit_cast(unsigned short, h);
  lo = __builtin_bit_cast(unsigned short, l);
}

// async global->LDS, 16B per lane; LDS dest = wave-uniform base + lane*16
__device__ __forceinline__ void gld16(const u16* g, u16* l) {
  __builtin_amdgcn_global_load_lds(
      (const __attribute__((address_space(1))) void*)g,
      (__attribute__((address_space(3))) void*)l, 16, 0, 0);
}

// bijective XCD-chunked remap of a 3D grid (requires nwg % 8 == 0; all our grids satisfy)
__device__ __forceinline__ void xcd_remap(int& bx, int& by, int& bz) {
  int gx = gridDim.x, gy = gridDim.y;
  int nwg = gx * gy * gridDim.z;
  int flat = (blockIdx.z * gy + blockIdx.y) * gx + blockIdx.x;
  int swz = ((nwg & 7) == 0) ? (flat & 7) * (nwg >> 3) + (flat >> 3) : flat;
  bx = swz % gx;
  int t1 = swz / gx;
  by = t1 % gy;
  bz = t1 / gy;
}

// ---------------- BatchNorm stats per channel over (B,S), fp64 ----------------
__global__ __launch_bounds__(256) void bn_stats_f64(const float* __restrict__ x, double* __restrict__ stats) {
  const int c = blockIdx.x;
  double s = 0.0, s2 = 0.0;
  for (int n = threadIdx.x; n < BB * SS; n += 256) {
    int b = n >> 10, sp = n & (SS - 1);
    double v = (double)x[((long long)(b * CC + c)) * SS + sp];
    s += v; s2 += v * v;
  }
  __shared__ double sh[256], sh2[256];
  sh[threadIdx.x] = s; sh2[threadIdx.x] = s2;
  __syncthreads();
  for (int off = 128; off > 0; off >>= 1) {
    if (threadIdx.x < off) { sh[threadIdx.x] += sh[threadIdx.x + off]; sh2[threadIdx.x] += sh2[threadIdx.x + off]; }
    __syncthreads();
  }
  if (threadIdx.x == 0) {
    double mean = sh[0] / 16384.0;
    double var = sh2[0] / 16384.0 - mean * mean;   // biased (torch BN)
    stats[c] = mean;
    stats[CC + c] = 1.0 / sqrt(var + 1e-5);
  }
}

// ---------------- normalize + transpose + split: x [b,c,s] -> xnh/xnl bf16 [b*S + s][c] ----------------
__global__ __launch_bounds__(256) void bn_apply_split(const float* __restrict__ x,
                                                      const double* __restrict__ stats,
                                                      u16* __restrict__ xnh, u16* __restrict__ xnl) {
  __shared__ float tile[64][65];
  const int b = blockIdx.z;
  const int s0 = blockIdx.x * 64, c0 = blockIdx.y * 64;
  const int t = threadIdx.x & 63, rb = threadIdx.x >> 6;
#pragma unroll
  for (int r0 = 0; r0 < 64; r0 += 4) {
    int r = r0 + rb;
    int c = c0 + r;
    double v = (double)x[((long long)(b * CC + c)) * SS + s0 + t];
    tile[r][t] = (float)((v - stats[c]) * stats[CC + c]);
  }
  __syncthreads();
#pragma unroll
  for (int r0 = 0; r0 < 64; r0 += 4) {
    int r = r0 + rb;
    long long idx = ((long long)(b * SS + s0 + r)) * CC + c0 + t;
    u16 h, l; split2(tile[t][r], h, l);
    xnh[idx] = h; xnl[idx] = l;
  }
}

// ---------------- fp32 [n] -> bf16 hi/lo planes ----------------
__global__ __launch_bounds__(256) void conv_split(const float* __restrict__ src,
                                                  u16* __restrict__ h, u16* __restrict__ l) {
  int i = (blockIdx.x * 256 + threadIdx.x) * 4;
  float4 f = *reinterpret_cast<const float4*>(src + i);
  ushort4 H, L;
  split2(f.x, H.x, L.x); split2(f.y, H.y, L.y); split2(f.z, H.z, L.z); split2(f.w, H.w, L.w);
  *reinterpret_cast<ushort4*>(h + i) = H;
  *reinterpret_cast<ushort4*>(l + i) = L;
}

// ---------------- V fp32 [c][d] -> Vt bf16 [d][c] ----------------
__global__ __launch_bounds__(256) void trans_conv_v(const float* __restrict__ V, u16* __restrict__ Vt) {
  __shared__ float tile[64][65];
  const int c0 = blockIdx.x * 64, d0 = blockIdx.y * 64;
  const int t = threadIdx.x & 63, rb = threadIdx.x >> 6;
#pragma unroll
  for (int r0 = 0; r0 < 64; r0 += 4) {
    int r = r0 + rb;
    tile[r][t] = V[(long long)(c0 + r) * 512 + d0 + t];
  }
  __syncthreads();
#pragma unroll
  for (int r0 = 0; r0 < 64; r0 += 4) {
    int r = r0 + rb;
    Vt[(long long)(d0 + r) * 512 + c0 + t] = f2bf(tile[t][r]);
  }
}

// ---------------- MFMA NT GEMM, 128x128 tile, BK=32, global_load_lds staging ----------------
// C[z][m][n] = sum_k A[z][m][k] * Bt[z][n][k]  (split planes approximate fp32 inputs; lo*lo dropped)
// OUTMODE 0: fp32 = acc*scale. 1: bf16. 2: split hi/lo to C,C2. 3: fp32 = acc + (Rh+Rl) residual.
template <bool ASPLIT, bool BSPLIT, int OUTMODE>
__global__ __launch_bounds__(256) void mfma_nt(
    const u16* __restrict__ Ah, const u16* __restrict__ Al, long long sA,
    const u16* __restrict__ Bh, const u16* __restrict__ Bl, long long sB,
    void* __restrict__ C, void* __restrict__ C2, long long sC,
    int N, int K, float scale, const u16* __restrict__ Rh, const u16* __restrict__ Rl) {
  __shared__ __attribute__((aligned(16))) u16 lah[128 * 32];
  __shared__ __attribute__((aligned(16))) u16 lal[ASPLIT ? 128 * 32 : 8];
  __shared__ __attribute__((aligned(16))) u16 lbh[128 * 32];
  __shared__ __attribute__((aligned(16))) u16 lbl[BSPLIT ? 128 * 32 : 8];

  const int tid = threadIdx.x;
  int bx, by, bz;
  xcd_remap(bx, by, bz);
  const int z = bz;
  const int m0 = by * 128, n0 = bx * 128;
  const int wave = tid >> 6, lane = tid & 63;
  const int wr = (wave >> 1) * 64, wc = (wave & 1) * 64;
  const int lrow = lane & 15, lquad = lane >> 4;
  const long long aB = (long long)z * sA, bB = (long long)z * sB;
  const int srow = tid >> 2, scg = (tid & 3) * 8;
  const int wofs = wave * 512;  // u16 units: wave-uniform LDS base (lane i lands at wofs*2 + i*16 bytes)

  f32x4 acc[4][4];
#pragma unroll
  for (int i = 0; i < 4; i++)
#pragma unroll
    for (int j = 0; j < 4; j++) acc[i][j] = (f32x4){0.f, 0.f, 0.f, 0.f};

  for (int k0 = 0; k0 < K; k0 += 32) {
    const long long ar1 = aB + (long long)(m0 + srow) * K + k0 + scg;
    const long long ar2 = aB + (long long)(m0 + srow + 64) * K + k0 + scg;
    gld16(Ah + ar1, &lah[wofs]);
    gld16(Ah + ar2, &lah[wofs + 2048]);
    if constexpr (ASPLIT) {
      gld16(Al + ar1, &lal[wofs]);
      gld16(Al + ar2, &lal[wofs + 2048]);
    }
    const long long br1 = bB + (long long)(n0 + srow) * K + k0 + scg;
    const long long br2 = bB + (long long)(n0 + srow + 64) * K + k0 + scg;
    gld16(Bh + br1, &lbh[wofs]);
    gld16(Bh + br2, &lbh[wofs + 2048]);
    if constexpr (BSPLIT) {
      gld16(Bl + br1, &lbl[wofs]);
      gld16(Bl + br2, &lbl[wofs + 2048]);
    }
    __syncthreads();

    bf16x8 ah[4], al[ASPLIT ? 4 : 1], bh[4], bl[BSPLIT ? 4 : 1];
#pragma unroll
    for (int i = 0; i < 4; i++) {
      ah[i] = *reinterpret_cast<const bf16x8*>(&lah[(wr + i * 16 + lrow) * 32 + lquad * 8]);
      if constexpr (ASPLIT)
        al[i] = *reinterpret_cast<const bf16x8*>(&lal[(wr + i * 16 + lrow) * 32 + lquad * 8]);
      bh[i] = *reinterpret_cast<const bf16x8*>(&lbh[(wc + i * 16 + lrow) * 32 + lquad * 8]);
      if constexpr (BSPLIT)
        bl[i] = *reinterpret_cast<const bf16x8*>(&lbl[(wc + i * 16 + lrow) * 32 + lquad * 8]);
    }
#pragma unroll
    for (int i = 0; i < 4; i++)
#pragma unroll
      for (int j = 0; j < 4; j++) {
        f32x4 t = acc[i][j];
        if constexpr (ASPLIT) t = __builtin_amdgcn_mfma_f32_16x16x32_bf16(al[i], bh[j], t, 0, 0, 0);
        if constexpr (BSPLIT) t = __builtin_amdgcn_mfma_f32_16x16x32_bf16(ah[i], bl[j], t, 0, 0, 0);
        t = __builtin_amdgcn_mfma_f32_16x16x32_bf16(ah[i], bh[j], t, 0, 0, 0);
        acc[i][j] = t;
      }
    __syncthreads();
  }

  const long long zC = (long long)z * sC;
#pragma unroll
  for (int i = 0; i < 4; i++) {
    int rl_ = wr + i * 16 + lquad * 4;
#pragma unroll
    for (int j = 0; j < 4; j++) {
      int col = n0 + wc + j * 16 + lrow;
#pragma unroll
      for (int r = 0; r < 4; r++) {
        long long idx = zC + (long long)(m0 + rl_ + r) * N + col;
        float val = acc[i][j][r];
        if constexpr (OUTMODE == 0) {
          reinterpret_cast<float*>(C)[idx] = val * scale;
        } else if constexpr (OUTMODE == 1) {
          reinterpret_cast<u16*>(C)[idx] = f2bf(val);
        } else if constexpr (OUTMODE == 2) {
          u16 h, l; split2(val, h, l);
          reinterpret_cast<u16*>(C)[idx] = h;
          reinterpret_cast<u16*>(C2)[idx] = l;
        } else {
          reinterpret_cast<float*>(C)[idx] = val + bf2f(Rh[idx]) + bf2f(Rl[idx]);
        }
      }
    }
  }
}

// ---------------- split x split MFMA NT GEMM, 256x256 tile, BK=32, 8 waves, ----------------
// double-buffered LDS, phase schedule with raw barriers + counted waits (T3+T4+T5).
// C fp32 = acc * scale. Bit-identical accumulation order to mfma_nt<true,true,0>.
__global__ __launch_bounds__(512, 2) void mfma_ss256(
    const u16* __restrict__ Ah, const u16* __restrict__ Al, long long sA,
    const u16* __restrict__ Bh, const u16* __restrict__ Bl, long long sB,
    float* __restrict__ C, long long sC, int N, int K, float scale) {
  // planes: 0=Ah 1=Al 2=Bh 3=Bl ; each [256 rows][32 k] u16 (16 KB); x2 buffers = 128 KiB
  __shared__ __attribute__((aligned(16))) u16 lds[2][4][256 * 32];

  const int tid = threadIdx.x;
  int bx, by, bz;
  xcd_remap(bx, by, bz);
  const int m0 = by * 256, n0 = bx * 256;
  const int wave = tid >> 6, lane = tid & 63;
  const int wr = (wave >> 2) * 128, wc = (wave & 3) * 64;   // 2M x 4N waves
  const int lrow = lane & 15, lquad = lane >> 4;
  const long long aB = (long long)bz * sA + (long long)m0 * K;
  const long long bB = (long long)bz * sB + (long long)n0 * K;
  const int srow = tid >> 2, scg = (tid & 3) * 8;           // srow 0..127
  const int wofs = wave * 512;                              // u16: rows 16w..16w+15

  f32x4 acc[8][4];
#pragma unroll
  for (int i = 0; i < 8; i++)
#pragma unroll
    for (int j = 0; j < 4; j++) acc[i][j] = (f32x4){0.f, 0.f, 0.f, 0.f};

  // stage helpers: A planes (rows m0.., both halves), B planes (rows n0..)
  auto stageA = [&](int buf, int k0) {
    const long long r1 = aB + (long long)srow * K + k0 + scg;
    const long long r2 = aB + (long long)(srow + 128) * K + k0 + scg;
    gld16(Ah + r1, &lds[buf][0][wofs]);
    gld16(Ah + r2, &lds[buf][0][4096 + wofs]);
    gld16(Al + r1, &lds[buf][1][wofs]);
    gld16(Al + r2, &lds[buf][1][4096 + wofs]);
  };
  auto stageB = [&](int buf, int k0) {
    const long long r1 = bB + (long long)srow * K + k0 + scg;
    const long long r2 = bB + (long long)(srow + 128) * K + k0 + scg;
    gld16(Bh + r1, &lds[buf][2][wofs]);
    gld16(Bh + r2, &lds[buf][2][4096 + wofs]);
    gld16(Bl + r1, &lds[buf][3][wofs]);
    gld16(Bl + r2, &lds[buf][3][4096 + wofs]);
  };

  // prologue: stage K-tile 0 into buf 0
  stageA(0, 0);
  stageB(0, 0);
  asm volatile("s_waitcnt vmcnt(0)" ::: "memory");
  __builtin_amdgcn_s_barrier();

  const int nkt = K >> 5;
  bf16x8 bh_[4], bl_[4];

  for (int kt = 0; kt < nkt; ++kt) {
    const int cur = kt & 1;
    const int nk0 = (kt + 1) << 5;
    const bool pf = (kt + 1) < nkt;

#pragma unroll
    for (int p = 0; p < 4; ++p) {
      // ds-load this phase's A sub-frags (and B frags in phase 0)
      bf16x8 a_h[2], a_l[2];
#pragma unroll
      for (int ii = 0; ii < 2; ++ii) {
        int row = wr + (2 * p + ii) * 16 + lrow;
        a_h[ii] = *reinterpret_cast<const bf16x8*>(&lds[cur][0][row * 32 + lquad * 8]);
        a_l[ii] = *reinterpret_cast<const bf16x8*>(&lds[cur][1][row * 32 + lquad * 8]);
      }
      if (p == 0) {
#pragma unroll
        for (int j = 0; j < 4; ++j) {
          int row = wc + j * 16 + lrow;
          bh_[j] = *reinterpret_cast<const bf16x8*>(&lds[cur][2][row * 32 + lquad * 8]);
          bl_[j] = *reinterpret_cast<const bf16x8*>(&lds[cur][3][row * 32 + lquad * 8]);
        }
      }
      // prefetch next K-tile (A in phase 0, B in phase 1)
      if (pf) {
        if (p == 0) stageA(cur ^ 1, nk0);
        else if (p == 1) stageB(cur ^ 1, nk0);
      }
      __builtin_amdgcn_sched_barrier(0);
      __builtin_amdgcn_s_barrier();
      asm volatile("s_waitcnt lgkmcnt(0)" ::: "memory");
      __builtin_amdgcn_sched_barrier(0);
      __builtin_amdgcn_s_setprio(1);
#pragma unroll
      for (int ii = 0; ii < 2; ++ii) {
        int i = 2 * p + ii;
#pragma unroll
        for (int j = 0; j < 4; ++j) {
          f32x4 t = acc[i][j];
          t = __builtin_amdgcn_mfma_f32_16x16x32_bf16(a_l[ii], bh_[j], t, 0, 0, 0);
          t = __builtin_amdgcn_mfma_f32_16x16x32_bf16(a_h[ii], bl_[j], t, 0, 0, 0);
          t = __builtin_amdgcn_mfma_f32_16x16x32_bf16(a_h[ii], bh_[j], t, 0, 0, 0);
          acc[i][j] = t;
        }
      }
      __builtin_amdgcn_s_setprio(0);
      if (p == 3) asm volatile("s_waitcnt vmcnt(0)" ::: "memory");
      __builtin_amdgcn_s_barrier();
    }
  }

  const long long zC = (long long)bz * sC;
#pragma unroll
  for (int i = 0; i < 8; i++) {
    int rl_ = wr + i * 16 + lquad * 4;
#pragma unroll
    for (int j = 0; j < 4; j++) {
      int col = n0 + wc + j * 16 + lrow;
#pragma unroll
      for (int r = 0; r < 4; r++) {
        C[zC + (long long)(m0 + rl_ + r) * N + col] = acc[i][j][r] * scale;
      }
    }
  }
}

// ---------------- softmax over batch axis: scomp fp32 -> attw bf16 ----------------
__global__ __launch_bounds__(256) void softmax_chunk(const float* __restrict__ sc,
                                                     u16* __restrict__ w, long long plane) {
  long long idx = (long long)blockIdx.x * 256 + threadIdx.x;
  float v[16];
  float m = -3.4e38f;
#pragma unroll
  for (int b = 0; b < 16; b++) { v[b] = sc[(long long)b * plane + idx]; m = fmaxf(m, v[b]); }
  float s = 0.f;
#pragma unroll
  for (int b = 0; b < 16; b++) { v[b] = expf(v[b] - m); s += v[b]; }
  float inv = 1.f / s;
#pragma unroll
  for (int b = 0; b < 16; b++) w[(long long)b * plane + idx] = f2bf(v[b] * inv);
}

extern "C" void kernel_launch(void* const* d_in, const int* in_sizes, int n_in,
                              void* d_out, int out_size, void* d_ws, size_t ws_size,
                              hipStream_t stream) {
  (void)in_sizes; (void)n_in; (void)out_size;
  const float* x  = (const float*)d_in[0];
  const float* Qw = (const float*)d_in[1];
  const float* Kw = (const float*)d_in[2];
  const float* Vw = (const float*)d_in[3];
  float* out = (float*)d_out;
  char* ws = (char*)d_ws;

  const float scale = 0.04419417382415922f;  // 1/sqrt(512)

  // ---- big layout (unchunked): needs 188,235,776 B ----
  if (ws_size >= 188235776ULL) {
    double* stats = (double*)(ws + 256);
    u16* xnh  = (u16*)(ws + 16384);
    u16* xnl  = (u16*)(ws + 16793600);
    u16* Vt   = (u16*)(ws + 33570816);
    u16* W2th = (u16*)(ws + 34095104);
    u16* W2tl = (u16*)(ws + 34619392);
    u16* Qh   = (u16*)(ws + 35143680);
    u16* Ql   = (u16*)(ws + 35667968);
    u16* Kh   = (u16*)(ws + 36192256);
    u16* Kl   = (u16*)(ws + 36716544);
    u16* vt   = (u16*)(ws + 37240832);   // [16,512,1024] bf16  16 MB
    u16* th   = (u16*)(ws + 54018048);   // [16,1024,512] hi    16 MB
    u16* tl   = (u16*)(ws + 70795264);   // lo                  16 MB
    float* scomp = (float*)(ws + 87572480);   // [16,1024,1024] fp32  64 MB
    u16* attw = (u16*)(ws + 154681344);  // [16,1024,1024] bf16  32 MB

    bn_stats_f64<<<CC, 256, 0, stream>>>(x, stats);
    bn_apply_split<<<dim3(16, 8, 16), 256, 0, stream>>>(x, stats, xnh, xnl);
    conv_split<<<256, 256, 0, stream>>>(Qw, Qh, Ql);
    conv_split<<<256, 256, 0, stream>>>(Kw, Kh, Kl);
    trans_conv_v<<<dim3(8, 8), 256, 0, stream>>>(Vw, Vt);

    // W2t[c'][c] = sum_d K[c',d] Q[c,d]
    mfma_nt<true, true, 2><<<dim3(4, 4, 1), 256, 0, stream>>>(
        Kh, Kl, 0, Qh, Ql, 0, W2th, W2tl, 0, 512, 512, 1.0f, nullptr, nullptr);

    // vt[b][d][token] = sum_c Vt[d,c] * xn[b,token,c]
    mfma_nt<false, true, 1><<<dim3(8, 4, 16), 256, 0, stream>>>(
        Vt, nullptr, 0, xnh, xnl, 524288, vt, nullptr, 524288, 1024, 512, 1.0f, nullptr, nullptr);

    // t[b,s,c'] = sum_c xn[b,s,c] * W2t[c'][c]   full S, 512 blocks
    mfma_nt<true, true, 2><<<dim3(4, 8, 16), 256, 0, stream>>>(
        xnh, xnl, 524288, W2th, W2tl, 0, th, tl, 524288, 512, 512, 1.0f, nullptr, nullptr);

    // scores[b,s,j] = scale * sum_c' t[b,s,c'] * xn[b,j,c']   256^2-tile 8-wave kernel, 256 blocks
    mfma_ss256<<<dim3(4, 4, 16), 512, 0, stream>>>(
        th, tl, 524288, xnh, xnl, 524288, scomp, 1048576, 1024, 512, scale);

    softmax_chunk<<<4096, 256, 0, stream>>>(scomp, attw, 1048576LL);

    // out[b,s,d] = sum_k attw[b,s,k] * vt[b,d,k] + xn residual   512 blocks
    mfma_nt<false, false, 3><<<dim3(4, 8, 16), 256, 0, stream>>>(
        attw, nullptr, 1048576, vt, nullptr, 524288,
        out, nullptr, 524288, 512, 1024, 1.0f, xnh, xnl);
    return;
  }

  // ---- fallback: proven chunked layout (85,475,328 B) ----
  double* stats = (double*)(ws + 256);
  u16* xnh  = (u16*)(ws + 16384);
  u16* xnl  = (u16*)(ws + 16793600);
  u16* Vt   = (u16*)(ws + 33570816);
  u16* W2th = (u16*)(ws + 34095104);
  u16* W2tl = (u16*)(ws + 34619392);
  u16* vt   = (u16*)(ws + 35143680);
  u16* th   = (u16*)(ws + 51920896);
  u16* tl   = (u16*)(ws + 56115200);
  float* scomp = (float*)(ws + 60309504);
  u16* attw = (u16*)(ws + 77086720);
  u16* Qh = (u16*)(ws + 51920896);
  u16* Ql = (u16*)(ws + 52445184);
  u16* Kh = (u16*)(ws + 52969472);
  u16* Kl = (u16*)(ws + 53493760);

  bn_stats_f64<<<CC, 256, 0, stream>>>(x, stats);
  bn_apply_split<<<dim3(16, 8, 16), 256, 0, stream>>>(x, stats, xnh, xnl);
  conv_split<<<256, 256, 0, stream>>>(Qw, Qh, Ql);
  conv_split<<<256, 256, 0, stream>>>(Kw, Kh, Kl);
  trans_conv_v<<<dim3(8, 8), 256, 0, stream>>>(Vw, Vt);

  mfma_nt<true, true, 2><<<dim3(4, 4, 1), 256, 0, stream>>>(
      Kh, Kl, 0, Qh, Ql, 0, W2th, W2tl, 0, 512, 512, 1.0f, nullptr, nullptr);

  mfma_nt<false, true, 1><<<dim3(8, 4, 16), 256, 0, stream>>>(
      Vt, nullptr, 0, xnh, xnl, 524288, vt, nullptr, 524288, 1024, 512, 1.0f, nullptr, nullptr);

  for (int ci = 0; ci < 4; ci++) {
    int s0c = ci * R;
    mfma_nt<true, true, 2><<<dim3(4, 2, 16), 256, 0, stream>>>(
        xnh + (long long)s0c * 512, xnl + (long long)s0c * 512, 524288,
        W2th, W2tl, 0, th, tl, 131072, 512, 512, 1.0f, nullptr, nullptr);
    mfma_nt<true, true, 0><<<dim3(8, 2, 16), 256, 0, stream>>>(
        th, tl, 131072, xnh, xnl, 524288, scomp, nullptr, 262144,
        1024, 512, scale, nullptr, nullptr);
    softmax_chunk<<<1024, 256, 0, stream>>>(scomp, attw, 262144LL);
    mfma_nt<false, false, 3><<<dim3(4, 2, 16), 256, 0, stream>>>(
        attw, nullptr, 262144, vt, nullptr, 524288,
        out + (long long)s0c * 512, nullptr, 524288, 512, 1024, 1.0f,
        xnh + (long long)s0c * 512, xnl + (long long)s0c * 512);
  }
}

// Round 3
// 311.181 us; speedup vs baseline: 1.7109x; 1.0161x over previous
//
#include <hip/hip_runtime.h>

typedef unsigned short u16;
typedef __bf16 bf16x8 __attribute__((ext_vector_type(8)));
typedef float f32x4 __attribute__((ext_vector_type(4)));

static constexpr int BB = 16;    // batch
static constexpr int CC = 512;   // channels
static constexpr int SS = 1024;  // seq
static constexpr int R  = 256;   // q-chunk rows (small-ws fallback path)

__device__ __forceinline__ u16 f2bf(float f) {
  __bf16 h = (__bf16)f; return __builtin_bit_cast(unsigned short, h);
}
__device__ __forceinline__ float bf2f(u16 u) {
  union { unsigned int i; float f; } v; v.i = ((unsigned int)u) << 16; return v.f;
}
__device__ __forceinline__ void split2(float v, u16& hi, u16& lo) {
  __bf16 h = (__bf16)v;
  float hf = (float)h;
  __bf16 l = (__bf16)(v - hf);
  hi = __builtin_bit_cast(unsigned short, h);
  lo = __builtin_bit_cast(unsigned short, l);
}

// async global->LDS, 16B per lane; LDS dest = wave-uniform base + lane*16
__device__ __forceinline__ void gld16(const u16* g, u16* l) {
  __builtin_amdgcn_global_load_lds(
      (const __attribute__((address_space(1))) void*)g,
      (__attribute__((address_space(3))) void*)l, 16, 0, 0);
}

// bijective XCD-chunked remap of a 3D grid (requires nwg % 8 == 0; all our grids satisfy)
__device__ __forceinline__ void xcd_remap(int& bx, int& by, int& bz) {
  int gx = gridDim.x, gy = gridDim.y;
  int nwg = gx * gy * gridDim.z;
  int flat = (blockIdx.z * gy + blockIdx.y) * gx + blockIdx.x;
  int swz = ((nwg & 7) == 0) ? (flat & 7) * (nwg >> 3) + (flat >> 3) : flat;
  bx = swz % gx;
  int t1 = swz / gx;
  by = t1 % gy;
  bz = t1 / gy;
}

// ---------------- BatchNorm stats per channel over (B,S), fp64 ----------------
__global__ __launch_bounds__(256) void bn_stats_f64(const float* __restrict__ x, double* __restrict__ stats) {
  const int c = blockIdx.x;
  double s = 0.0, s2 = 0.0;
  for (int n = threadIdx.x; n < BB * SS; n += 256) {
    int b = n >> 10, sp = n & (SS - 1);
    double v = (double)x[((long long)(b * CC + c)) * SS + sp];
    s += v; s2 += v * v;
  }
  __shared__ double sh[256], sh2[256];
  sh[threadIdx.x] = s; sh2[threadIdx.x] = s2;
  __syncthreads();
  for (int off = 128; off > 0; off >>= 1) {
    if (threadIdx.x < off) { sh[threadIdx.x] += sh[threadIdx.x + off]; sh2[threadIdx.x] += sh2[threadIdx.x + off]; }
    __syncthreads();
  }
  if (threadIdx.x == 0) {
    double mean = sh[0] / 16384.0;
    double var = sh2[0] / 16384.0 - mean * mean;   // biased (torch BN)
    stats[c] = mean;
    stats[CC + c] = 1.0 / sqrt(var + 1e-5);
  }
}

// ---------------- normalize + transpose + split: x [b,c,s] -> xnh/xnl bf16 [b*S + s][c] ----------------
__global__ __launch_bounds__(256) void bn_apply_split(const float* __restrict__ x,
                                                      const double* __restrict__ stats,
                                                      u16* __restrict__ xnh, u16* __restrict__ xnl) {
  __shared__ float tile[64][65];
  const int b = blockIdx.z;
  const int s0 = blockIdx.x * 64, c0 = blockIdx.y * 64;
  const int t = threadIdx.x & 63, rb = threadIdx.x >> 6;
#pragma unroll
  for (int r0 = 0; r0 < 64; r0 += 4) {
    int r = r0 + rb;
    int c = c0 + r;
    double v = (double)x[((long long)(b * CC + c)) * SS + s0 + t];
    tile[r][t] = (float)((v - stats[c]) * stats[CC + c]);
  }
  __syncthreads();
#pragma unroll
  for (int r0 = 0; r0 < 64; r0 += 4) {
    int r = r0 + rb;
    long long idx = ((long long)(b * SS + s0 + r)) * CC + c0 + t;
    u16 h, l; split2(tile[t][r], h, l);
    xnh[idx] = h; xnl[idx] = l;
  }
}

// ---------------- fp32 [n] -> bf16 hi/lo planes ----------------
__global__ __launch_bounds__(256) void conv_split(const float* __restrict__ src,
                                                  u16* __restrict__ h, u16* __restrict__ l) {
  int i = (blockIdx.x * 256 + threadIdx.x) * 4;
  float4 f = *reinterpret_cast<const float4*>(src + i);
  ushort4 H, L;
  split2(f.x, H.x, L.x); split2(f.y, H.y, L.y); split2(f.z, H.z, L.z); split2(f.w, H.w, L.w);
  *reinterpret_cast<ushort4*>(h + i) = H;
  *reinterpret_cast<ushort4*>(l + i) = L;
}

// ---------------- V fp32 [c][d] -> Vt bf16 [d][c] ----------------
__global__ __launch_bounds__(256) void trans_conv_v(const float* __restrict__ V, u16* __restrict__ Vt) {
  __shared__ float tile[64][65];
  const int c0 = blockIdx.x * 64, d0 = blockIdx.y * 64;
  const int t = threadIdx.x & 63, rb = threadIdx.x >> 6;
#pragma unroll
  for (int r0 = 0; r0 < 64; r0 += 4) {
    int r = r0 + rb;
    tile[r][t] = V[(long long)(c0 + r) * 512 + d0 + t];
  }
  __syncthreads();
#pragma unroll
  for (int r0 = 0; r0 < 64; r0 += 4) {
    int r = r0 + rb;
    Vt[(long long)(d0 + r) * 512 + c0 + t] = f2bf(tile[t][r]);
  }
}

// ---------------- MFMA NT GEMM, 128x128 tile, BK=32, global_load_lds staging ----------------
// (kept for W2t + fallback path)
template <bool ASPLIT, bool BSPLIT, int OUTMODE>
__global__ __launch_bounds__(256) void mfma_nt(
    const u16* __restrict__ Ah, const u16* __restrict__ Al, long long sA,
    const u16* __restrict__ Bh, const u16* __restrict__ Bl, long long sB,
    void* __restrict__ C, void* __restrict__ C2, long long sC,
    int N, int K, float scale, const u16* __restrict__ Rh, const u16* __restrict__ Rl) {
  __shared__ __attribute__((aligned(16))) u16 lah[128 * 32];
  __shared__ __attribute__((aligned(16))) u16 lal[ASPLIT ? 128 * 32 : 8];
  __shared__ __attribute__((aligned(16))) u16 lbh[128 * 32];
  __shared__ __attribute__((aligned(16))) u16 lbl[BSPLIT ? 128 * 32 : 8];

  const int tid = threadIdx.x;
  int bx, by, bz;
  xcd_remap(bx, by, bz);
  const int z = bz;
  const int m0 = by * 128, n0 = bx * 128;
  const int wave = tid >> 6, lane = tid & 63;
  const int wr = (wave >> 1) * 64, wc = (wave & 1) * 64;
  const int lrow = lane & 15, lquad = lane >> 4;
  const long long aB = (long long)z * sA, bB = (long long)z * sB;
  const int srow = tid >> 2, scg = (tid & 3) * 8;
  const int wofs = wave * 512;

  f32x4 acc[4][4];
#pragma unroll
  for (int i = 0; i < 4; i++)
#pragma unroll
    for (int j = 0; j < 4; j++) acc[i][j] = (f32x4){0.f, 0.f, 0.f, 0.f};

  for (int k0 = 0; k0 < K; k0 += 32) {
    const long long ar1 = aB + (long long)(m0 + srow) * K + k0 + scg;
    const long long ar2 = aB + (long long)(m0 + srow + 64) * K + k0 + scg;
    gld16(Ah + ar1, &lah[wofs]);
    gld16(Ah + ar2, &lah[wofs + 2048]);
    if constexpr (ASPLIT) {
      gld16(Al + ar1, &lal[wofs]);
      gld16(Al + ar2, &lal[wofs + 2048]);
    }
    const long long br1 = bB + (long long)(n0 + srow) * K + k0 + scg;
    const long long br2 = bB + (long long)(n0 + srow + 64) * K + k0 + scg;
    gld16(Bh + br1, &lbh[wofs]);
    gld16(Bh + br2, &lbh[wofs + 2048]);
    if constexpr (BSPLIT) {
      gld16(Bl + br1, &lbl[wofs]);
      gld16(Bl + br2, &lbl[wofs + 2048]);
    }
    __syncthreads();

    bf16x8 ah[4], al[ASPLIT ? 4 : 1], bh[4], bl[BSPLIT ? 4 : 1];
#pragma unroll
    for (int i = 0; i < 4; i++) {
      ah[i] = *reinterpret_cast<const bf16x8*>(&lah[(wr + i * 16 + lrow) * 32 + lquad * 8]);
      if constexpr (ASPLIT)
        al[i] = *reinterpret_cast<const bf16x8*>(&lal[(wr + i * 16 + lrow) * 32 + lquad * 8]);
      bh[i] = *reinterpret_cast<const bf16x8*>(&lbh[(wc + i * 16 + lrow) * 32 + lquad * 8]);
      if constexpr (BSPLIT)
        bl[i] = *reinterpret_cast<const bf16x8*>(&lbl[(wc + i * 16 + lrow) * 32 + lquad * 8]);
    }
#pragma unroll
    for (int i = 0; i < 4; i++)
#pragma unroll
      for (int j = 0; j < 4; j++) {
        f32x4 t = acc[i][j];
        if constexpr (ASPLIT) t = __builtin_amdgcn_mfma_f32_16x16x32_bf16(al[i], bh[j], t, 0, 0, 0);
        if constexpr (BSPLIT) t = __builtin_amdgcn_mfma_f32_16x16x32_bf16(ah[i], bl[j], t, 0, 0, 0);
        t = __builtin_amdgcn_mfma_f32_16x16x32_bf16(ah[i], bh[j], t, 0, 0, 0);
        acc[i][j] = t;
      }
    __syncthreads();
  }

  const long long zC = (long long)z * sC;
#pragma unroll
  for (int i = 0; i < 4; i++) {
    int rl_ = wr + i * 16 + lquad * 4;
#pragma unroll
    for (int j = 0; j < 4; j++) {
      int col = n0 + wc + j * 16 + lrow;
#pragma unroll
      for (int r = 0; r < 4; r++) {
        long long idx = zC + (long long)(m0 + rl_ + r) * N + col;
        float val = acc[i][j][r];
        if constexpr (OUTMODE == 0) {
          reinterpret_cast<float*>(C)[idx] = val * scale;
        } else if constexpr (OUTMODE == 1) {
          reinterpret_cast<u16*>(C)[idx] = f2bf(val);
        } else if constexpr (OUTMODE == 2) {
          u16 h, l; split2(val, h, l);
          reinterpret_cast<u16*>(C)[idx] = h;
          reinterpret_cast<u16*>(C2)[idx] = l;
        } else {
          reinterpret_cast<float*>(C)[idx] = val + bf2f(Rh[idx]) + bf2f(Rl[idx]);
        }
      }
    }
  }
}

// ---------------- pipelined MFMA NT GEMM: BM x 256 tile, BK=32, 8 waves, dbuf LDS, ----------------
// phase schedule (raw barriers + counted waits + setprio) and bank-conflict-free LDS via
// source-side XOR swizzle (slot' = slot ^ ((row>>1)&3)); LDS dest stays linear for global_load_lds.
// Accumulation order identical to mfma_nt (al*bh, ah*bl, ah*bh; k ascending) -> bit-identical output.
template <int BM, int APL, int BPL, int OUTMODE, int PHASES, int MW>
__global__ __launch_bounds__(512, MW) void mfma_pipe(
    const u16* __restrict__ Ah, const u16* __restrict__ Al, long long sA,
    const u16* __restrict__ Bh, const u16* __restrict__ Bl, long long sB,
    void* __restrict__ C, void* __restrict__ C2, long long sC,
    int N, int K, float scale, const u16* __restrict__ Rh, const u16* __restrict__ Rl) {
  constexpr int MI = BM / 32;         // i-blocks per wave (wave covers BM/2 rows)
  constexpr int IPP = MI / PHASES;    // i-blocks per phase
  __shared__ __attribute__((aligned(16))) u16 la[2][APL * BM * 32];
  __shared__ __attribute__((aligned(16))) u16 lb[2][BPL * 256 * 32];

  const int tid = threadIdx.x;
  int bx, by, bz;
  xcd_remap(bx, by, bz);
  const int m0 = by * BM, n0 = bx * 256;
  const int wave = tid >> 6, lane = tid & 63;
  const int wr = (wave >> 2) * (BM / 2), wc = (wave & 3) * 64;  // 2M x 4N waves
  const int lrow = lane & 15, lquad = lane >> 4;
  const long long aB = (long long)bz * sA + (long long)m0 * K;
  const long long bB = (long long)bz * sB + (long long)n0 * K;
  const int srow = tid >> 2;                                    // 0..127
  const int scg = ((tid & 3) ^ ((srow >> 1) & 3)) * 8;          // swizzled source chunk
  const int wofs = wave * 512;                                  // u16: 1 KiB per wave

  f32x4 acc[MI][4];
#pragma unroll
  for (int i = 0; i < MI; i++)
#pragma unroll
    for (int j = 0; j < 4; j++) acc[i][j] = (f32x4){0.f, 0.f, 0.f, 0.f};

  auto stageA = [&](int buf, int k0) {
#pragma unroll
    for (int pl = 0; pl < APL; ++pl) {
      const u16* src = pl ? Al : Ah;
      gld16(src + aB + (long long)srow * K + k0 + scg, &la[buf][pl * BM * 32 + wofs]);
      if constexpr (BM == 256)
        gld16(src + aB + (long long)(srow + 128) * K + k0 + scg, &la[buf][pl * BM * 32 + 4096 + wofs]);
    }
  };
  auto stageB = [&](int buf, int k0) {
#pragma unroll
    for (int pl = 0; pl < BPL; ++pl) {
      const u16* src = pl ? Bl : Bh;
      gld16(src + bB + (long long)srow * K + k0 + scg, &lb[buf][pl * 256 * 32 + wofs]);
      gld16(src + bB + (long long)(srow + 128) * K + k0 + scg, &lb[buf][pl * 256 * 32 + 4096 + wofs]);
    }
  };
  auto rdA = [&](int buf, int pl, int row) -> bf16x8 {
    return *reinterpret_cast<const bf16x8*>(
        &la[buf][pl * BM * 32 + row * 32 + (lquad ^ ((row >> 1) & 3)) * 8]);
  };
  auto rdB = [&](int buf, int pl, int row) -> bf16x8 {
    return *reinterpret_cast<const bf16x8*>(
        &lb[buf][pl * 256 * 32 + row * 32 + (lquad ^ ((row >> 1) & 3)) * 8]);
  };

  // prologue: stage K-tile 0 into buf 0
  stageA(0, 0);
  stageB(0, 0);
  asm volatile("s_waitcnt vmcnt(0)" ::: "memory");
  __builtin_amdgcn_s_barrier();

  const int nkt = K >> 5;
  bf16x8 bh_[4], bl_[BPL == 2 ? 4 : 1];

  for (int kt = 0; kt < nkt; ++kt) {
    const int cur = kt & 1;
    const int nk0 = (kt + 1) << 5;
    const bool pf = (kt + 1) < nkt;

#pragma unroll
    for (int p = 0; p < PHASES; ++p) {
      bf16x8 a_h[IPP], a_l[IPP];
#pragma unroll
      for (int ii = 0; ii < IPP; ++ii) {
        int row = wr + (p * IPP + ii) * 16 + lrow;
        a_h[ii] = rdA(cur, 0, row);
        if constexpr (APL == 2) a_l[ii] = rdA(cur, 1, row);
      }
      if (p == 0) {
#pragma unroll
        for (int j = 0; j < 4; ++j) {
          int row = wc + j * 16 + lrow;
          bh_[j] = rdB(cur, 0, row);
          if constexpr (BPL == 2) bl_[j] = rdB(cur, 1, row);
        }
      }
      if (pf) {
        if constexpr (PHASES == 1) {
          stageA(cur ^ 1, nk0);
          stageB(cur ^ 1, nk0);
        } else {
          if (p == 0) stageA(cur ^ 1, nk0);
          else if (p == 1) stageB(cur ^ 1, nk0);
        }
      }
      __builtin_amdgcn_sched_barrier(0);
      __builtin_amdgcn_s_barrier();
      asm volatile("s_waitcnt lgkmcnt(0)" ::: "memory");
      __builtin_amdgcn_sched_barrier(0);
      __builtin_amdgcn_s_setprio(1);
#pragma unroll
      for (int ii = 0; ii < IPP; ++ii) {
        int i = p * IPP + ii;
#pragma unroll
        for (int j = 0; j < 4; ++j) {
          f32x4 t = acc[i][j];
          if constexpr (APL == 2) t = __builtin_amdgcn_mfma_f32_16x16x32_bf16(a_l[ii], bh_[j], t, 0, 0, 0);
          if constexpr (BPL == 2) t = __builtin_amdgcn_mfma_f32_16x16x32_bf16(a_h[ii], bl_[j], t, 0, 0, 0);
          t = __builtin_amdgcn_mfma_f32_16x16x32_bf16(a_h[ii], bh_[j], t, 0, 0, 0);
          acc[i][j] = t;
        }
      }
      __builtin_amdgcn_s_setprio(0);
      if (p == PHASES - 1) asm volatile("s_waitcnt vmcnt(0)" ::: "memory");
      __builtin_amdgcn_s_barrier();
    }
  }

  const long long zC = (long long)bz * sC;
#pragma unroll
  for (int i = 0; i < MI; i++) {
    int rl_ = wr + i * 16 + lquad * 4;
#pragma unroll
    for (int j = 0; j < 4; j++) {
      int col = n0 + wc + j * 16 + lrow;
#pragma unroll
      for (int r = 0; r < 4; r++) {
        long long idx = zC + (long long)(m0 + rl_ + r) * N + col;
        float val = acc[i][j][r];
        if constexpr (OUTMODE == 0) {
          reinterpret_cast<float*>(C)[idx] = val * scale;
        } else if constexpr (OUTMODE == 1) {
          reinterpret_cast<u16*>(C)[idx] = f2bf(val);
        } else if constexpr (OUTMODE == 2) {
          u16 h, l; split2(val, h, l);
          reinterpret_cast<u16*>(C)[idx] = h;
          reinterpret_cast<u16*>(C2)[idx] = l;
        } else {
          reinterpret_cast<float*>(C)[idx] = val + bf2f(Rh[idx]) + bf2f(Rl[idx]);
        }
      }
    }
  }
}

// ---------------- softmax over batch axis: scomp fp32 -> attw bf16 (scalar, fallback) ----------------
__global__ __launch_bounds__(256) void softmax_chunk(const float* __restrict__ sc,
                                                     u16* __restrict__ w, long long plane) {
  long long idx = (long long)blockIdx.x * 256 + threadIdx.x;
  float v[16];
  float m = -3.4e38f;
#pragma unroll
  for (int b = 0; b < 16; b++) { v[b] = sc[(long long)b * plane + idx]; m = fmaxf(m, v[b]); }
  float s = 0.f;
#pragma unroll
  for (int b = 0; b < 16; b++) { v[b] = expf(v[b] - m); s += v[b]; }
  float inv = 1.f / s;
#pragma unroll
  for (int b = 0; b < 16; b++) w[(long long)b * plane + idx] = f2bf(v[b] * inv);
}

// ---------------- softmax over batch axis, float4-vectorized ----------------
__global__ __launch_bounds__(256) void softmax_chunk4(const float* __restrict__ sc,
                                                      u16* __restrict__ w, long long plane) {
  long long idx = ((long long)blockIdx.x * 256 + threadIdx.x) * 4;
  float4 v[16];
  float4 m = make_float4(-3.4e38f, -3.4e38f, -3.4e38f, -3.4e38f);
#pragma unroll
  for (int b = 0; b < 16; b++) {
    v[b] = *reinterpret_cast<const float4*>(sc + (long long)b * plane + idx);
    m.x = fmaxf(m.x, v[b].x); m.y = fmaxf(m.y, v[b].y);
    m.z = fmaxf(m.z, v[b].z); m.w = fmaxf(m.w, v[b].w);
  }
  float4 s = make_float4(0.f, 0.f, 0.f, 0.f);
#pragma unroll
  for (int b = 0; b < 16; b++) {
    v[b].x = expf(v[b].x - m.x); s.x += v[b].x;
    v[b].y = expf(v[b].y - m.y); s.y += v[b].y;
    v[b].z = expf(v[b].z - m.z); s.z += v[b].z;
    v[b].w = expf(v[b].w - m.w); s.w += v[b].w;
  }
  float4 inv = make_float4(1.f / s.x, 1.f / s.y, 1.f / s.z, 1.f / s.w);
#pragma unroll
  for (int b = 0; b < 16; b++) {
    ushort4 o;
    o.x = f2bf(v[b].x * inv.x); o.y = f2bf(v[b].y * inv.y);
    o.z = f2bf(v[b].z * inv.z); o.w = f2bf(v[b].w * inv.w);
    *reinterpret_cast<ushort4*>(w + (long long)b * plane + idx) = o;
  }
}

extern "C" void kernel_launch(void* const* d_in, const int* in_sizes, int n_in,
                              void* d_out, int out_size, void* d_ws, size_t ws_size,
                              hipStream_t stream) {
  (void)in_sizes; (void)n_in; (void)out_size;
  const float* x  = (const float*)d_in[0];
  const float* Qw = (const float*)d_in[1];
  const float* Kw = (const float*)d_in[2];
  const float* Vw = (const float*)d_in[3];
  float* out = (float*)d_out;
  char* ws = (char*)d_ws;

  const float scale = 0.04419417382415922f;  // 1/sqrt(512)

  // ---- big layout (unchunked): needs 188,235,776 B ----
  if (ws_size >= 188235776ULL) {
    double* stats = (double*)(ws + 256);
    u16* xnh  = (u16*)(ws + 16384);
    u16* xnl  = (u16*)(ws + 16793600);
    u16* Vt   = (u16*)(ws + 33570816);
    u16* W2th = (u16*)(ws + 34095104);
    u16* W2tl = (u16*)(ws + 34619392);
    u16* Qh   = (u16*)(ws + 35143680);
    u16* Ql   = (u16*)(ws + 35667968);
    u16* Kh   = (u16*)(ws + 36192256);
    u16* Kl   = (u16*)(ws + 36716544);
    u16* vt   = (u16*)(ws + 37240832);   // [16,512,1024] bf16  16 MB
    u16* th   = (u16*)(ws + 54018048);   // [16,1024,512] hi    16 MB
    u16* tl   = (u16*)(ws + 70795264);   // lo                  16 MB
    float* scomp = (float*)(ws + 87572480);   // [16,1024,1024] fp32  64 MB
    u16* attw = (u16*)(ws + 154681344);  // [16,1024,1024] bf16  32 MB

    bn_stats_f64<<<CC, 256, 0, stream>>>(x, stats);
    bn_apply_split<<<dim3(16, 8, 16), 256, 0, stream>>>(x, stats, xnh, xnl);
    conv_split<<<256, 256, 0, stream>>>(Qw, Qh, Ql);
    conv_split<<<256, 256, 0, stream>>>(Kw, Kh, Kl);
    trans_conv_v<<<dim3(8, 8), 256, 0, stream>>>(Vw, Vt);

    // W2t[c'][c] = sum_d K[c',d] Q[c,d]   (small; 128^2 kernel)
    mfma_nt<true, true, 2><<<dim3(4, 4, 1), 256, 0, stream>>>(
        Kh, Kl, 0, Qh, Ql, 0, W2th, W2tl, 0, 512, 512, 1.0f, nullptr, nullptr);

    // vt[b][d][token] = sum_c Vt[d,c] * xn[b,token,c]   128x256 tiles, 256 blocks, 2 blk/CU
    mfma_pipe<128, 1, 2, 1, 2, 4><<<dim3(4, 4, 16), 512, 0, stream>>>(
        Vt, nullptr, 0, xnh, xnl, 524288, vt, nullptr, 524288, 1024, 512, 1.0f, nullptr, nullptr);

    // t[b,s,c'] = sum_c xn[b,s,c] * W2t[c'][c]   128x256 tiles, 256 blocks
    mfma_pipe<128, 2, 2, 2, 2, 2><<<dim3(2, 8, 16), 512, 0, stream>>>(
        xnh, xnl, 524288, W2th, W2tl, 0, th, tl, 524288, 512, 512, 1.0f, nullptr, nullptr);

    // scores[b,s,j] = scale * sum_c' t[b,s,c'] * xn[b,j,c']   256x256 tiles, 256 blocks
    mfma_pipe<256, 2, 2, 0, 4, 2><<<dim3(4, 4, 16), 512, 0, stream>>>(
        th, tl, 524288, xnh, xnl, 524288, scomp, nullptr, 1048576, 1024, 512, scale, nullptr, nullptr);

    softmax_chunk4<<<1024, 256, 0, stream>>>(scomp, attw, 1048576LL);

    // out[b,s,d] = sum_k attw[b,s,k] * vt[b,d,k] + xn residual   128x256 tiles, 256 blocks
    mfma_pipe<128, 1, 1, 3, 1, 4><<<dim3(2, 8, 16), 512, 0, stream>>>(
        attw, nullptr, 1048576, vt, nullptr, 524288,
        out, nullptr, 524288, 512, 1024, 1.0f, xnh, xnl);
    return;
  }

  // ---- fallback: proven chunked layout (85,475,328 B) ----
  double* stats = (double*)(ws + 256);
  u16* xnh  = (u16*)(ws + 16384);
  u16* xnl  = (u16*)(ws + 16793600);
  u16* Vt   = (u16*)(ws + 33570816);
  u16* W2th = (u16*)(ws + 34095104);
  u16* W2tl = (u16*)(ws + 34619392);
  u16* vt   = (u16*)(ws + 35143680);
  u16* th   = (u16*)(ws + 51920896);
  u16* tl   = (u16*)(ws + 56115200);
  float* scomp = (float*)(ws + 60309504);
  u16* attw = (u16*)(ws + 77086720);
  u16* Qh = (u16*)(ws + 51920896);
  u16* Ql = (u16*)(ws + 52445184);
  u16* Kh = (u16*)(ws + 52969472);
  u16* Kl = (u16*)(ws + 53493760);

  bn_stats_f64<<<CC, 256, 0, stream>>>(x, stats);
  bn_apply_split<<<dim3(16, 8, 16), 256, 0, stream>>>(x, stats, xnh, xnl);
  conv_split<<<256, 256, 0, stream>>>(Qw, Qh, Ql);
  conv_split<<<256, 256, 0, stream>>>(Kw, Kh, Kl);
  trans_conv_v<<<dim3(8, 8), 256, 0, stream>>>(Vw, Vt);

  mfma_nt<true, true, 2><<<dim3(4, 4, 1), 256, 0, stream>>>(
      Kh, Kl, 0, Qh, Ql, 0, W2th, W2tl, 0, 512, 512, 1.0f, nullptr, nullptr);

  mfma_nt<false, true, 1><<<dim3(8, 4, 16), 256, 0, stream>>>(
      Vt, nullptr, 0, xnh, xnl, 524288, vt, nullptr, 524288, 1024, 512, 1.0f, nullptr, nullptr);

  for (int ci = 0; ci < 4; ci++) {
    int s0c = ci * R;
    mfma_nt<true, true, 2><<<dim3(4, 2, 16), 256, 0, stream>>>(
        xnh + (long long)s0c * 512, xnl + (long long)s0c * 512, 524288,
        W2th, W2tl, 0, th, tl, 131072, 512, 512, 1.0f, nullptr, nullptr);
    mfma_nt<true, true, 0><<<dim3(8, 2, 16), 256, 0, stream>>>(
        th, tl, 131072, xnh, xnl, 524288, scomp, nullptr, 262144,
        1024, 512, scale, nullptr, nullptr);
    softmax_chunk<<<1024, 256, 0, stream>>>(scomp, attw, 262144LL);
    mfma_nt<false, false, 3><<<dim3(4, 2, 16), 256, 0, stream>>>(
        attw, nullptr, 262144, vt, nullptr, 524288,
        out + (long long)s0c * 512, nullptr, 524288, 512, 1024, 1.0f,
        xnh + (long long)s0c * 512, xnl + (long long)s0c * 512);
  }
}